// Round 13
// baseline (701.714 us; speedup 1.0000x reference)
//
#include <hip/hip_runtime.h>

typedef __attribute__((ext_vector_type(8))) __bf16 bf16x8;
typedef __attribute__((ext_vector_type(4))) float f32x4;

#define DEV __device__ __forceinline__

DEV unsigned short f2bf(float f) {
  unsigned u = __float_as_uint(f);
  u = (u + 0x7fffu + ((u >> 16) & 1u)) >> 16;   // round-to-nearest-even
  return (unsigned short)u;
}
DEV float bf2f(unsigned short s) { return __uint_as_float(((unsigned)s) << 16); }
DEV float sigm(float x) { return 1.f / (1.f + expf(-x)); }

DEV uint4 pack8(f32x4 a, f32x4 b) {
  uint4 o;
  o.x = (unsigned)f2bf(a[0]) | ((unsigned)f2bf(a[1]) << 16);
  o.y = (unsigned)f2bf(a[2]) | ((unsigned)f2bf(a[3]) << 16);
  o.z = (unsigned)f2bf(b[0]) | ((unsigned)f2bf(b[1]) << 16);
  o.w = (unsigned)f2bf(b[2]) | ((unsigned)f2bf(b[3]) << 16);
  return o;
}

#define GL16(SRC, LDSB)                                                                    \
  __builtin_amdgcn_global_load_lds(                                                       \
      (const __attribute__((address_space(1))) unsigned int*)(SRC),                       \
      (__attribute__((address_space(3))) unsigned int*)(LDSB), 16, 0, 0)

// ---------------------------------------------------------------------------
// GEMM: C[M x N] = A[M x K] * B^T  (B stored [N x K] row-major bf16)
// R8-proven: 128x128 tile, BK=64, 4 waves, dbuf 64KB LDS, counted vmcnt(8)
// + raw s_barrier. XOR swizzle involution (rule #21).
// Grid: x = N tiles, y = M tiles. MODE: 0 f32 out, 1 bf16 out.
// ---------------------------------------------------------------------------
template<int MODE, bool BIAS>
__global__ __launch_bounds__(256)
void gemm_bt(const unsigned short* __restrict__ A, const unsigned short* __restrict__ Bm,
             const float* __restrict__ bias, void* __restrict__ Cv,
             int M, int N, int K)
{
  __shared__ unsigned short sm[32768];          // 64 KB: 2 x {As[128][64], Bs[128][64]}

  const int tid  = threadIdx.x;
  const int lane = tid & 63;
  const int wv   = tid >> 6;
  const int wr   = (wv >> 1) << 6;              // wave row offset (0/64)
  const int wc   = (wv & 1) << 6;               // wave col offset (0/64)
  const long mTile = (long)blockIdx.y << 7;
  const long nTile = (long)blockIdx.x << 7;

  const f32x4 z4 = {0.f, 0.f, 0.f, 0.f};
  f32x4 acc[4][4];
  #pragma unroll
  for (int i = 0; i < 4; ++i)
    #pragma unroll
    for (int j = 0; j < 4; ++j) acc[i][j] = z4;

  const int crow = lane >> 3;                   // row within 8-row chunk
  const int ckb  = (lane & 7) << 4;             // linear kbyte of this lane's 16B

  auto stage = [&](int buf, int k0) {           // exactly 8 gload_lds per thread
    char* base = (char*)sm + (buf << 15);
    #pragma unroll
    for (int i = 0; i < 4; ++i) {
      const int c   = (wv << 2) + i;            // chunk 0..15
      const int row = (c << 3) + crow;          // tile row 0..127
      const int kb  = ckb ^ ((row & 7) << 4);   // pre-swizzled source kbyte
      const unsigned short* sA = A + (mTile + row) * K + k0 + (kb >> 1);
      GL16(sA, base + (c << 10));
      int bn = (int)nTile + row; bn = bn < N ? bn : (N - 1);   // clamp OOB cols
      const unsigned short* sB = Bm + (long)bn * K + k0 + (kb >> 1);
      GL16(sB, base + 16384 + (c << 10));
    }
  };

  const int nt = K >> 6;
  stage(0, 0);
  int cur = 0;
  for (int t = 0; t < nt; ++t) {
    if (t + 1 < nt) {
      stage(cur ^ 1, (t + 1) << 6);             // prefetch: stays in flight
      asm volatile("s_waitcnt vmcnt(8)" ::: "memory");   // tile t landed
    } else {
      asm volatile("s_waitcnt vmcnt(0)" ::: "memory");
    }
    __builtin_amdgcn_s_barrier();               // raw: does NOT drain vmcnt
    asm volatile("" ::: "memory");
    const char* As = (const char*)sm + (cur << 15);
    const char* Bs = As + 16384;
    #pragma unroll
    for (int kk = 0; kk < 64; kk += 32) {
      const int kbl = (kk + ((lane >> 4) << 3)) << 1;   // logical kbyte of fragment
      bf16x8 af[4], bfv[4];
      #pragma unroll
      for (int mi = 0; mi < 4; ++mi) {
        const int rr = wr + (mi << 4) + (lane & 15);
        af[mi] = *(const bf16x8*)(As + (rr << 7) + (kbl ^ ((rr & 7) << 4)));
      }
      #pragma unroll
      for (int ni = 0; ni < 4; ++ni) {
        const int rr = wc + (ni << 4) + (lane & 15);
        bfv[ni] = *(const bf16x8*)(Bs + (rr << 7) + (kbl ^ ((rr & 7) << 4)));
      }
      #pragma unroll
      for (int mi = 0; mi < 4; ++mi)
        #pragma unroll
        for (int ni = 0; ni < 4; ++ni)
          acc[mi][ni] = __builtin_amdgcn_mfma_f32_16x16x32_bf16(af[mi], bfv[ni], acc[mi][ni], 0, 0, 0);
    }
    asm volatile("" ::: "memory");              // pin ds_reads above barrier
    __builtin_amdgcn_s_barrier();               // buf free for stage(t+2)
    cur ^= 1;
  }

  // C/D layout col=lane&15, row=(lane>>4)*4+j (m89-verified)
  #pragma unroll
  for (int ni = 0; ni < 4; ++ni) {
    const long col = nTile + wc + (ni << 4) + (lane & 15);
    if (col < N) {
      float bv = 0.f;
      if constexpr (BIAS) bv = bias[col];
      #pragma unroll
      for (int mi = 0; mi < 4; ++mi) {
        const long row = mTile + wr + (mi << 4) + ((lane >> 4) << 2);
        #pragma unroll
        for (int j = 0; j < 4; ++j) {
          const float v = acc[mi][ni][j] + bv;
          if constexpr (MODE == 1) ((unsigned short*)Cv)[(row + j) * N + col] = f2bf(v);
          else                     ((float*)Cv)[(row + j) * N + col] = v;
        }
      }
    }
  }
}

// ---------------------------------------------------------------------------
// 256x256-tile GEMM (R9-proven counted-vmcnt schedule): 8 waves (2x4),
// per-wave 128x64 output, acc[8][4], 128KB dynamic LDS dbuf (128KB is fast;
// 160KB is a cliff — R4/R5/R10).
// MODE 0 (scores, R13): 1-D grid + bijective XCD chunking (m204), M-fast
// within chunk (all 16 M-tiles of an N-panel on one XCD -> panel L2-reuse),
// and NON-TEMPORAL C stores (819MB streaming write bypasses L2, keeping
// embb panels resident). MODE 2: fused-alpha partials (unchanged from R12).
// ---------------------------------------------------------------------------
template<int MODE>
__global__ __launch_bounds__(512, 2)
void gemm256(const unsigned short* __restrict__ A, const unsigned short* __restrict__ Bm,
             void* __restrict__ Cv, const float* __restrict__ vw1,
             const float* __restrict__ qwf, const int* __restrict__ batchp,
             int M, int N, int K)
{
  extern __shared__ unsigned short smd[];       // 128 KB: 2 x {As[256][64], Bs[256][64]}
  const int tid  = threadIdx.x;
  const int lane = tid & 63;
  const int wv   = tid >> 6;                    // 0..7
  const int wr   = (wv >> 2) << 7;              // wave row offset (0/128)
  const int wc   = (wv & 3) << 6;               // wave col offset (0/64/128/192)

  long mTile, nTile;
  if constexpr (MODE == 0) {
    // bijective XCD chunk (nwg % 8 == 0 guaranteed by launch), M-fast inside
    const int q = gridDim.x >> 3;
    const int wgid = (blockIdx.x & 7) * q + (blockIdx.x >> 3);
    const int MB = M >> 8;
    mTile = (long)(wgid & (MB - 1)) << 8;       // MB is a power of 2 (16)
    nTile = (long)(wgid / MB) << 8;
  } else {
    mTile = (long)blockIdx.y << 8;
    nTile = (long)blockIdx.x << 8;
  }

  const f32x4 z4 = {0.f, 0.f, 0.f, 0.f};
  f32x4 acc[8][4];
  #pragma unroll
  for (int i = 0; i < 8; ++i)
    #pragma unroll
    for (int j = 0; j < 4; ++j) acc[i][j] = z4;

  const int crow = lane >> 3;                   // row within 8-row chunk
  const int ckb  = (lane & 7) << 4;

  auto stage = [&](int buf, int k0) {           // exactly 8 gload_lds per thread
    char* base = (char*)smd + (buf << 16);
    #pragma unroll
    for (int i = 0; i < 4; ++i) {
      const int c   = (wv << 2) + i;            // chunk 0..31
      const int row = (c << 3) + crow;          // tile row 0..255
      const int kb  = ckb ^ ((row & 7) << 4);
      const unsigned short* sA = A + (mTile + row) * K + k0 + (kb >> 1);
      GL16(sA, base + (c << 10));
      int bn = (int)nTile + row; bn = bn < N ? bn : (N - 1);
      const unsigned short* sB = Bm + (long)bn * K + k0 + (kb >> 1);
      GL16(sB, base + 32768 + (c << 10));
    }
  };

  const int nt = K >> 6;
  stage(0, 0);
  int cur = 0;
  for (int t = 0; t < nt; ++t) {
    if (t + 1 < nt) {
      stage(cur ^ 1, (t + 1) << 6);
      asm volatile("s_waitcnt vmcnt(8)" ::: "memory");
    } else {
      asm volatile("s_waitcnt vmcnt(0)" ::: "memory");
    }
    __builtin_amdgcn_s_barrier();
    asm volatile("" ::: "memory");
    const char* As = (const char*)smd + (cur << 16);
    const char* Bs = As + 32768;
    #pragma unroll
    for (int kk = 0; kk < 64; kk += 32) {
      const int kbl = (kk + ((lane >> 4) << 3)) << 1;
      bf16x8 af[8], bfv[4];
      #pragma unroll
      for (int mi = 0; mi < 8; ++mi) {
        const int rr = wr + (mi << 4) + (lane & 15);
        af[mi] = *(const bf16x8*)(As + (rr << 7) + (kbl ^ ((rr & 7) << 4)));
      }
      #pragma unroll
      for (int ni = 0; ni < 4; ++ni) {
        const int rr = wc + (ni << 4) + (lane & 15);
        bfv[ni] = *(const bf16x8*)(Bs + (rr << 7) + (kbl ^ ((rr & 7) << 4)));
      }
      #pragma unroll
      for (int mi = 0; mi < 8; ++mi)
        #pragma unroll
        for (int ni = 0; ni < 4; ++ni)
          acc[mi][ni] = __builtin_amdgcn_mfma_f32_16x16x32_bf16(af[mi], bfv[ni], acc[mi][ni], 0, 0, 0);
    }
    asm volatile("" ::: "memory");
    __builtin_amdgcn_s_barrier();
    cur ^= 1;
  }

  if constexpr (MODE == 2) {
    // fused alpha: slice = col-quarter (wc>>6); partial over this wave's 64 cols
    const int slice = wc >> 6;
    #pragma unroll
    for (int mi = 0; mi < 8; ++mi) {
      #pragma unroll
      for (int j = 0; j < 4; ++j) {
        const long row = mTile + wr + (mi << 4) + ((lane >> 4) << 2) + j;
        const long vb = (long)batchp[row] << 8;
        float part = 0.f;
        #pragma unroll
        for (int ni = 0; ni < 4; ++ni) {
          const int col = (int)nTile + wc + (ni << 4) + (lane & 15);
          part += sigm(acc[mi][ni][j] + vw1[vb + col]) * qwf[col];
        }
        #pragma unroll
        for (int off = 1; off < 16; off <<= 1) part += __shfl_xor(part, off, 64);
        if ((lane & 15) == 0) ((float*)Cv)[(long)slice * M + row] = part;
      }
    }
  } else {
    float* C = (float*)Cv;
    #pragma unroll
    for (int ni = 0; ni < 4; ++ni) {
      const long col = nTile + wc + (ni << 4) + (lane & 15);
      if (col < N) {
        #pragma unroll
        for (int mi = 0; mi < 8; ++mi) {
          const long row = mTile + wr + (mi << 4) + ((lane >> 4) << 2);
          #pragma unroll
          for (int j = 0; j < 4; ++j)
            __builtin_nontemporal_store(acc[mi][ni][j], &C[(row + j) * N + col]);
        }
      }
    }
  }
}

// ---------------------------------------------------------------------------
// Fused dual-GEMM + GRUCell:  h' = GRU(aggh @ Wp^T + bih, h @ whh^T + bhh, h)
// R12-proven OCCUPANCY variant: block = 128 rows x 32 dims (8 D0-blocks),
// 8 waves (4 row-groups x 2 dim-halves), acc[2][6], ~119 VGPR under
// __launch_bounds__(512,4) -> 2 BLOCKS/CU; inter-block TLP hides drains.
// HARD RULE: no 160KB dbuf (R4/R5/R10 all +420us). LDS 56KB static.
// ---------------------------------------------------------------------------
__global__ __launch_bounds__(512, 4)
void k_ggru(const unsigned short* __restrict__ agg, const unsigned short* __restrict__ hin,
            const unsigned short* __restrict__ wpb, const unsigned short* __restrict__ whhb,
            const float* __restrict__ bih, const float* __restrict__ bhh,
            unsigned short* __restrict__ hout)
{
  __shared__ unsigned short sm[28672];          // 56 KB
  const int tid  = threadIdx.x;
  const int lane = tid & 63;
  const int wv   = tid >> 6;                    // 0..7
  const int rg   = wv >> 1;                     // row group (0..3, 32 rows each)
  const int dh   = wv & 1;                      // dim half (0/1, 16 dims)
  const int D0   = blockIdx.x << 5;             // hidden-dim base (0..224, step 32)
  const long mTile = (long)blockIdx.y << 7;

  const f32x4 z4 = {0.f, 0.f, 0.f, 0.f};
  f32x4 acc[2][6];
  #pragma unroll
  for (int i = 0; i < 2; ++i)
    #pragma unroll
    for (int g = 0; g < 6; ++g) acc[i][g] = z4;

  const int crow = lane >> 3;
  const int ckb  = (lane & 7) << 4;

  for (int k0 = 0; k0 < 256; k0 += 64) {
    // stage 56 x 1KB chunks; wave wv owns chunks wv*7 .. wv*7+6
    #pragma unroll
    for (int i = 0; i < 7; ++i) {
      const int c = wv * 7 + i;
      if (c < 32) {                             // A tiles (aggh then h), 16 chunks each
        const unsigned short* src = (c < 16) ? agg : hin;
        const int row = ((c & 15) << 3) + crow;
        const int kb  = ckb ^ ((row & 7) << 4);
        GL16(src + (mTile + row) * 256 + k0 + (kb >> 1), (char*)sm + (c << 10));
      } else {                                  // B gate chunks: 6 gates x 4 chunks
        const int g  = (c - 32) >> 2;           // 0..5
        const int lr = (((c - 32) & 3) << 3) + crow;   // 0..31
        const unsigned short* Ws = (g < 3) ? wpb : whhb;
        const long grow = (long)((g % 3) * 256 + D0 + lr);
        const int kb = ckb ^ ((lr & 7) << 4);
        GL16(Ws + grow * 256 + k0 + (kb >> 1), (char*)sm + (c << 10));
      }
    }
    __syncthreads();
    #pragma unroll
    for (int kk = 0; kk < 64; kk += 32) {
      const int kbl = (kk + ((lane >> 4) << 3)) << 1;
      bf16x8 fa[2], fh[2], fb[6];
      #pragma unroll
      for (int mi = 0; mi < 2; ++mi) {
        const int r = (rg << 5) + (mi << 4) + (lane & 15);
        const int off = (r << 7) + (kbl ^ ((r & 7) << 4));
        fa[mi] = *(const bf16x8*)((const char*)sm + off);
        fh[mi] = *(const bf16x8*)((const char*)sm + 16384 + off);
      }
      const int lr = (dh << 4) + (lane & 15);
      const int boff = (lr << 7) + (kbl ^ ((lr & 7) << 4));
      #pragma unroll
      for (int g = 0; g < 6; ++g)
        fb[g] = *(const bf16x8*)((const char*)sm + 32768 + (g << 12) + boff);
      #pragma unroll
      for (int mi = 0; mi < 2; ++mi) {
        #pragma unroll
        for (int g = 0; g < 3; ++g)
          acc[mi][g] = __builtin_amdgcn_mfma_f32_16x16x32_bf16(fa[mi], fb[g], acc[mi][g], 0, 0, 0);
        #pragma unroll
        for (int g = 3; g < 6; ++g)
          acc[mi][g] = __builtin_amdgcn_mfma_f32_16x16x32_bf16(fh[mi], fb[g], acc[mi][g], 0, 0, 0);
      }
    }
    __syncthreads();
  }

  // GRU combine (per-lane local) + write h'
  const int d = D0 + (dh << 4) + (lane & 15);
  const float bir = bih[d], biz = bih[256 + d], bin_ = bih[512 + d];
  const float bhr = bhh[d], bhz = bhh[256 + d], bhn  = bhh[512 + d];
  #pragma unroll
  for (int mi = 0; mi < 2; ++mi) {
    #pragma unroll
    for (int j = 0; j < 4; ++j) {
      const long row = mTile + (rg << 5) + (mi << 4) + ((lane >> 4) << 2) + j;
      const float hold = bf2f(hin[row * 256 + d]);
      const float r  = sigm(acc[mi][0][j] + bir + acc[mi][3][j] + bhr);
      const float z  = sigm(acc[mi][1][j] + biz + acc[mi][4][j] + bhz);
      const float n  = tanhf(acc[mi][2][j] + bin_ + r * (acc[mi][5][j] + bhn));
      hout[row * 256 + d] = f2bf((1.f - z) * n + z * hold);
    }
  }
}

// ---------------------------------------------------------------------------
// Mega-prep: one launch for emb->bf16, embedding gather, all weight cvt,
// gw straight copy, b1+b2. Block ranges:
//   [0, V8) emb cvt | [V8, V8+Nn8) gather | tail: weights/b12/gw
// ---------------------------------------------------------------------------
__global__ void k_pre(const int* __restrict__ x, const float* __restrict__ emb,
                      unsigned short* __restrict__ embb, unsigned short* __restrict__ h,
                      const float* __restrict__ wih, const float* __restrict__ whh,
                      const float* __restrict__ W1, const float* __restrict__ W2,
                      const float* __restrict__ W3, const float* __restrict__ b1,
                      const float* __restrict__ b2, const float* __restrict__ gw,
                      unsigned short* __restrict__ wihb, unsigned short* __restrict__ whhb,
                      unsigned short* __restrict__ w1b, unsigned short* __restrict__ w2b,
                      unsigned short* __restrict__ w3b, float* __restrict__ b12,
                      unsigned short* __restrict__ gwb, int V8, int Nn8)
{
  const int b = blockIdx.x, t = threadIdx.x;
  if (b < V8) {
    const long i = (long)b * 256 + t;           // one per 8 elems of emb
    const f32x4 a = *(const f32x4*)(emb + i * 8);
    const f32x4 c = *(const f32x4*)(emb + i * 8 + 4);
    *(uint4*)(embb + i * 8) = pack8(a, c);
  } else if (b < V8 + Nn8) {
    const long i = (long)(b - V8) * 256 + t;    // one per 8 dims of h
    const long node = i >> 5;
    const int  d0 = ((int)i & 31) << 3;
    const long row = (long)x[node] - 1;         // 1-based ids
    const float* p = emb + row * 256 + d0;
    const f32x4 a = *(const f32x4*)p;
    const f32x4 c = *(const f32x4*)(p + 4);
    *(uint4*)(h + node * 256 + d0) = pack8(a, c);
  } else {
    const int bw = b - V8 - Nn8;
    const float* src; unsigned short* dst; long base;
    if (bw < 96)       { src = wih; dst = wihb; base = bw; }
    else if (bw < 192) { src = whh; dst = whhb; base = bw - 96; }
    else if (bw < 224) { src = W1;  dst = w1b;  base = bw - 192; }
    else if (bw < 256) { src = W2;  dst = w2b;  base = bw - 224; }
    else if (bw < 320) { src = W3;  dst = w3b;  base = bw - 256; }
    else if (bw == 320) { b12[t] = b1[t] + b2[t]; return; }
    else               { src = gw;  dst = gwb;  base = bw - 321; }
    const long i = base * 256 + t;
    const f32x4 a = *(const f32x4*)(src + i * 8);
    const f32x4 c = *(const f32x4*)(src + i * 8 + 4);
    *(uint4*)(dst + i * 8) = pack8(a, c);
  }
}

// per-graph scatter-add: block g handles its 20 nodes / 40 edges; thread owns dim d
__global__ void k_scatter(const unsigned short* __restrict__ m, const int* __restrict__ ei,
                          unsigned short* __restrict__ agg, int E)
{
  __shared__ float aggs[20 * 256];
  __shared__ int es[40], ed[40];
  const int g = blockIdx.x;
  const int d = threadIdx.x;
  if (d < 40) es[d] = ei[g * 40 + d];
  if (d >= 128 && d < 168) ed[d - 128] = ei[E + g * 40 + (d - 128)];
  #pragma unroll
  for (int i = 0; i < 20; ++i) aggs[i * 256 + d] = 0.f;
  __syncthreads();
  for (int e = 0; e < 40; ++e) {
    const float mv = bf2f(m[(long)es[e] * 256 + d]);
    const int loc = ed[e] - g * 20;
    aggs[loc * 256 + d] += mv;     // thread-private column: no races
  }
  const long base = (long)g * (20 * 256);
  #pragma unroll
  for (int i = 0; i < 20; ++i)
    agg[base + i * 256 + d] = f2bf(aggs[i * 256 + d]);
}

// v_n gather + cat[ :256] write; last-node index via inline binsearch on batch
__global__ void k_vn(const unsigned short* __restrict__ h, const int* __restrict__ batch,
                     unsigned short* __restrict__ vn, unsigned short* __restrict__ cat, int n)
{
  const long i = (long)blockIdx.x * 256 + threadIdx.x;
  const long g = i >> 5;
  const int  d0 = ((int)i & 31) << 3;
  int lo = 0, hi = n;                     // first idx with batch[idx] > g
  while (lo < hi) { const int mid = (lo + hi) >> 1; if (batch[mid] > (int)g) hi = mid; else lo = mid + 1; }
  const uint4 v = *(const uint4*)(h + (long)(lo - 1) * 256 + d0);
  *(uint4*)(vn + g * 256 + d0) = v;
  *(uint4*)(cat + g * 512 + d0) = v;
}

__global__ void k_sg(const float* __restrict__ alph2, const float* __restrict__ qb,
                     const unsigned short* __restrict__ h, unsigned short* __restrict__ cat, int Nn)
{
  __shared__ float al[20];
  const int g = blockIdx.x, d = threadIdx.x;
  if (d < 20) {
    const int n = g * 20 + d;
    al[d] = qb[0] + alph2[n] + alph2[Nn + n] + alph2[2 * Nn + n] + alph2[3 * Nn + n];
  }
  __syncthreads();
  float s = 0.f;
  const unsigned short* hp = h + (long)g * 20 * 256 + d;
  #pragma unroll
  for (int i = 0; i < 20; ++i) s += al[i] * bf2f(hp[i * 256]);
  cat[(long)g * 512 + 256 + d] = f2bf(s);
}

// ---------------------------------------------------------------------------
extern "C" void kernel_launch(void* const* d_in, const int* in_sizes, int n_in,
                              void* d_out, int out_size, void* d_ws, size_t ws_size,
                              hipStream_t stream)
{
  const int*   x     = (const int*)  d_in[0];
  const int*   ei    = (const int*)  d_in[1];
  const int*   batch = (const int*)  d_in[2];
  const float* emb   = (const float*)d_in[3];
  const float* gw    = (const float*)d_in[4];
  const float* wih   = (const float*)d_in[5];
  const float* whh   = (const float*)d_in[6];
  const float* bih   = (const float*)d_in[7];
  const float* bhh   = (const float*)d_in[8];
  const float* W1    = (const float*)d_in[9];
  const float* b1    = (const float*)d_in[10];
  const float* W2    = (const float*)d_in[11];
  const float* b2    = (const float*)d_in[12];
  const float* qw    = (const float*)d_in[13];
  const float* qb    = (const float*)d_in[14];
  const float* W3    = (const float*)d_in[15];
  const float* b3    = (const float*)d_in[16];

  const int Nn = in_sizes[0];           // 81920 nodes
  const int E  = in_sizes[1] / 2;       // 163840 edges
  const int V  = in_sizes[3] / 256;     // 50000 vocab
  const int B  = out_size / V;          // 4096 graphs

  char* w = (char*)d_ws;
  auto take = [&](size_t bytes) { char* r = w; w += (bytes + 1023) & ~(size_t)1023; return r; };
  unsigned short* h_   = (unsigned short*)take((size_t)Nn * 256 * 2);
  unsigned short* m_   = (unsigned short*)take((size_t)Nn * 256 * 2);
  unsigned short* agg_ = (unsigned short*)take((size_t)Nn * 256 * 2);
  unsigned short* embb = (unsigned short*)take((size_t)V * 256 * 2);
  unsigned short* gwb  = (unsigned short*)take((size_t)2 * 65536 * 2);
  unsigned short* wihb = (unsigned short*)take((size_t)768 * 256 * 2);
  unsigned short* whhb = (unsigned short*)take((size_t)768 * 256 * 2);
  unsigned short* wp0  = (unsigned short*)take((size_t)768 * 256 * 2);
  unsigned short* wp1  = (unsigned short*)take((size_t)768 * 256 * 2);
  unsigned short* w1b  = (unsigned short*)take((size_t)65536 * 2);
  unsigned short* w2b  = (unsigned short*)take((size_t)65536 * 2);
  unsigned short* w3b  = (unsigned short*)take((size_t)131072 * 2);
  unsigned short* vnb  = (unsigned short*)take((size_t)B * 256 * 2);
  unsigned short* catb = (unsigned short*)take((size_t)B * 512 * 2);
  unsigned short* shb  = (unsigned short*)take((size_t)B * 256 * 2);
  float*          b12  = (float*)take(256 * 4);
  float*          alph2= (float*)take((size_t)4 * Nn * 4);
  float*          vw1  = (float*)take((size_t)B * 256 * 4);

  const int MBn = Nn / 128;             // 640
  const int MBb = B / 128;              // 32
  const int V8  = V / 8;                // 6250
  const int Nn8 = Nn / 8;               // 10240
  const int MB2 = B / 256;              // 16
  const int NB2 = (V + 255) / 256;      // 196

  // --- prep (single launch): emb cvt + gather + weight cvt ---
  k_pre<<<dim3(V8 + Nn8 + 385), 256, 0, stream>>>(x, emb, embb, h_,
      wih, whh, W1, W2, W3, b1, b2, gw, wihb, whhb, w1b, w2b, w3b, b12, gwb, V8, Nn8);

  // --- fused layer weights: Wp[i] = wih @ gw[i]^T  (768x256, tiny) ---
  gemm_bt<1, false><<<dim3(2, 6), 256, 0, stream>>>(wihb, gwb, nullptr, wp0, 768, 256, 256);
  gemm_bt<1, false><<<dim3(2, 6), 256, 0, stream>>>(wihb, gwb + 65536, nullptr, wp1, 768, 256, 256);

  // --- 2x GatedGraphConv + fused GRUCell (h ping-pongs h_ <-> m_) ---
  // m-GEMM eliminated: gi = scatter(h) @ Wp^T  (associativity of linear ops)
  unsigned short* hc = h_;
  unsigned short* mb = m_;
  for (int L = 0; L < 2; ++L) {
    k_scatter<<<dim3(B), 256, 0, stream>>>(hc, ei, agg_, E);
    k_ggru<<<dim3(8, MBn), 512, 0, stream>>>(agg_, hc, (L == 0 ? wp0 : wp1), whhb,
                                             bih, bhh, mb);
    unsigned short* t = hc; hc = mb; mb = t;    // h' now lives in old m buffer
  }
  // after 2 swaps hc == h_ again

  // --- attention readout ---
  k_vn<<<dim3(B * 32 / 256), 256, 0, stream>>>(hc, batch, vnb, catb, Nn);
  gemm_bt<0, true><<<dim3(2, MBb), 256, 0, stream>>>(vnb, w1b, b12, vw1, B, 256, 256);
  // fused alpha on the 256^2 schedule: grid (1, Nn/256)
  gemm256<2><<<dim3(1, Nn / 256), 512, 131072, stream>>>(hc, w2b, alph2,
                                                         vw1, qw, batch, Nn, 256, 256);
  k_sg<<<dim3(B), 256, 0, stream>>>(alph2, qb, hc, catb, Nn);
  gemm_bt<1, true><<<dim3(2, MBb), 256, 0, stream>>>(catb, w3b, b3, shb, B, 256, 512);

  // --- scores = s_h @ emb^T -> d_out (f32); 256^2-tile, 1-D grid with
  // bijective XCD chunking + NT stores (R13) ---
  gemm256<0><<<dim3(NB2 * MB2), 512, 131072, stream>>>(shb, embb, (float*)d_out,
                                                       nullptr, nullptr, nullptr, B, V, 256);

  (void)n_in; (void)ws_size;
}

// Round 14
// 684.564 us; speedup vs baseline: 1.0251x; 1.0251x over previous
//
#include <hip/hip_runtime.h>

typedef __attribute__((ext_vector_type(8))) __bf16 bf16x8;
typedef __attribute__((ext_vector_type(4))) float f32x4;

#define DEV __device__ __forceinline__

DEV unsigned short f2bf(float f) {
  unsigned u = __float_as_uint(f);
  u = (u + 0x7fffu + ((u >> 16) & 1u)) >> 16;   // round-to-nearest-even
  return (unsigned short)u;
}
DEV float bf2f(unsigned short s) { return __uint_as_float(((unsigned)s) << 16); }
DEV float sigm(float x) { return 1.f / (1.f + expf(-x)); }

DEV uint4 pack8(f32x4 a, f32x4 b) {
  uint4 o;
  o.x = (unsigned)f2bf(a[0]) | ((unsigned)f2bf(a[1]) << 16);
  o.y = (unsigned)f2bf(a[2]) | ((unsigned)f2bf(a[3]) << 16);
  o.z = (unsigned)f2bf(b[0]) | ((unsigned)f2bf(b[1]) << 16);
  o.w = (unsigned)f2bf(b[2]) | ((unsigned)f2bf(b[3]) << 16);
  return o;
}

#define GL16(SRC, LDSB)                                                                    \
  __builtin_amdgcn_global_load_lds(                                                       \
      (const __attribute__((address_space(1))) unsigned int*)(SRC),                       \
      (__attribute__((address_space(3))) unsigned int*)(LDSB), 16, 0, 0)

// ---------------------------------------------------------------------------
// GEMM: C[M x N] = A[M x K] * B^T  (B stored [N x K] row-major bf16)
// R8-proven: 128x128 tile, BK=64, 4 waves, dbuf 64KB LDS, counted vmcnt(8)
// + raw s_barrier. XOR swizzle involution (rule #21).
// Grid: x = N tiles, y = M tiles. MODE: 0 f32 out, 1 bf16 out.
// ---------------------------------------------------------------------------
template<int MODE, bool BIAS>
__global__ __launch_bounds__(256)
void gemm_bt(const unsigned short* __restrict__ A, const unsigned short* __restrict__ Bm,
             const float* __restrict__ bias, void* __restrict__ Cv,
             int M, int N, int K)
{
  __shared__ unsigned short sm[32768];          // 64 KB: 2 x {As[128][64], Bs[128][64]}

  const int tid  = threadIdx.x;
  const int lane = tid & 63;
  const int wv   = tid >> 6;
  const int wr   = (wv >> 1) << 6;              // wave row offset (0/64)
  const int wc   = (wv & 1) << 6;               // wave col offset (0/64)
  const long mTile = (long)blockIdx.y << 7;
  const long nTile = (long)blockIdx.x << 7;

  const f32x4 z4 = {0.f, 0.f, 0.f, 0.f};
  f32x4 acc[4][4];
  #pragma unroll
  for (int i = 0; i < 4; ++i)
    #pragma unroll
    for (int j = 0; j < 4; ++j) acc[i][j] = z4;

  const int crow = lane >> 3;                   // row within 8-row chunk
  const int ckb  = (lane & 7) << 4;             // linear kbyte of this lane's 16B

  auto stage = [&](int buf, int k0) {           // exactly 8 gload_lds per thread
    char* base = (char*)sm + (buf << 15);
    #pragma unroll
    for (int i = 0; i < 4; ++i) {
      const int c   = (wv << 2) + i;            // chunk 0..15
      const int row = (c << 3) + crow;          // tile row 0..127
      const int kb  = ckb ^ ((row & 7) << 4);   // pre-swizzled source kbyte
      const unsigned short* sA = A + (mTile + row) * K + k0 + (kb >> 1);
      GL16(sA, base + (c << 10));
      int bn = (int)nTile + row; bn = bn < N ? bn : (N - 1);   // clamp OOB cols
      const unsigned short* sB = Bm + (long)bn * K + k0 + (kb >> 1);
      GL16(sB, base + 16384 + (c << 10));
    }
  };

  const int nt = K >> 6;
  stage(0, 0);
  int cur = 0;
  for (int t = 0; t < nt; ++t) {
    if (t + 1 < nt) {
      stage(cur ^ 1, (t + 1) << 6);             // prefetch: stays in flight
      asm volatile("s_waitcnt vmcnt(8)" ::: "memory");   // tile t landed
    } else {
      asm volatile("s_waitcnt vmcnt(0)" ::: "memory");
    }
    __builtin_amdgcn_s_barrier();               // raw: does NOT drain vmcnt
    asm volatile("" ::: "memory");
    const char* As = (const char*)sm + (cur << 15);
    const char* Bs = As + 16384;
    #pragma unroll
    for (int kk = 0; kk < 64; kk += 32) {
      const int kbl = (kk + ((lane >> 4) << 3)) << 1;   // logical kbyte of fragment
      bf16x8 af[4], bfv[4];
      #pragma unroll
      for (int mi = 0; mi < 4; ++mi) {
        const int rr = wr + (mi << 4) + (lane & 15);
        af[mi] = *(const bf16x8*)(As + (rr << 7) + (kbl ^ ((rr & 7) << 4)));
      }
      #pragma unroll
      for (int ni = 0; ni < 4; ++ni) {
        const int rr = wc + (ni << 4) + (lane & 15);
        bfv[ni] = *(const bf16x8*)(Bs + (rr << 7) + (kbl ^ ((rr & 7) << 4)));
      }
      #pragma unroll
      for (int mi = 0; mi < 4; ++mi)
        #pragma unroll
        for (int ni = 0; ni < 4; ++ni)
          acc[mi][ni] = __builtin_amdgcn_mfma_f32_16x16x32_bf16(af[mi], bfv[ni], acc[mi][ni], 0, 0, 0);
    }
    asm volatile("" ::: "memory");              // pin ds_reads above barrier
    __builtin_amdgcn_s_barrier();               // buf free for stage(t+2)
    cur ^= 1;
  }

  // C/D layout col=lane&15, row=(lane>>4)*4+j (m89-verified)
  #pragma unroll
  for (int ni = 0; ni < 4; ++ni) {
    const long col = nTile + wc + (ni << 4) + (lane & 15);
    if (col < N) {
      float bv = 0.f;
      if constexpr (BIAS) bv = bias[col];
      #pragma unroll
      for (int mi = 0; mi < 4; ++mi) {
        const long row = mTile + wr + (mi << 4) + ((lane >> 4) << 2);
        #pragma unroll
        for (int j = 0; j < 4; ++j) {
          const float v = acc[mi][ni][j] + bv;
          if constexpr (MODE == 1) ((unsigned short*)Cv)[(row + j) * N + col] = f2bf(v);
          else                     ((float*)Cv)[(row + j) * N + col] = v;
        }
      }
    }
  }
}

// ---------------------------------------------------------------------------
// 256x256-tile GEMM (R9-proven counted-vmcnt schedule): 8 waves (2x4),
// per-wave 128x64 output, acc[8][4], 128KB dynamic LDS dbuf (128KB is fast;
// 160KB is a cliff — R4/R5/R10). 2-D grid (x = N tiles, y = M tiles) with
// PLAIN stores — R13's NT-store + XCD-chunk variant regressed +21us; reverted.
// MODE 0: f32 C out. MODE 2: fused-alpha partials (sigm(vw1+x).qw per
// col-quarter slice); k_sg sums the 4 slices.
// ---------------------------------------------------------------------------
template<int MODE>
__global__ __launch_bounds__(512, 2)
void gemm256(const unsigned short* __restrict__ A, const unsigned short* __restrict__ Bm,
             void* __restrict__ Cv, const float* __restrict__ vw1,
             const float* __restrict__ qwf, const int* __restrict__ batchp,
             int M, int N, int K)
{
  extern __shared__ unsigned short smd[];       // 128 KB: 2 x {As[256][64], Bs[256][64]}
  const int tid  = threadIdx.x;
  const int lane = tid & 63;
  const int wv   = tid >> 6;                    // 0..7
  const int wr   = (wv >> 2) << 7;              // wave row offset (0/128)
  const int wc   = (wv & 3) << 6;               // wave col offset (0/64/128/192)
  const long mTile = (long)blockIdx.y << 8;
  const long nTile = (long)blockIdx.x << 8;

  const f32x4 z4 = {0.f, 0.f, 0.f, 0.f};
  f32x4 acc[8][4];
  #pragma unroll
  for (int i = 0; i < 8; ++i)
    #pragma unroll
    for (int j = 0; j < 4; ++j) acc[i][j] = z4;

  const int crow = lane >> 3;                   // row within 8-row chunk
  const int ckb  = (lane & 7) << 4;

  auto stage = [&](int buf, int k0) {           // exactly 8 gload_lds per thread
    char* base = (char*)smd + (buf << 16);
    #pragma unroll
    for (int i = 0; i < 4; ++i) {
      const int c   = (wv << 2) + i;            // chunk 0..31
      const int row = (c << 3) + crow;          // tile row 0..255
      const int kb  = ckb ^ ((row & 7) << 4);
      const unsigned short* sA = A + (mTile + row) * K + k0 + (kb >> 1);
      GL16(sA, base + (c << 10));
      int bn = (int)nTile + row; bn = bn < N ? bn : (N - 1);
      const unsigned short* sB = Bm + (long)bn * K + k0 + (kb >> 1);
      GL16(sB, base + 32768 + (c << 10));
    }
  };

  const int nt = K >> 6;
  stage(0, 0);
  int cur = 0;
  for (int t = 0; t < nt; ++t) {
    if (t + 1 < nt) {
      stage(cur ^ 1, (t + 1) << 6);
      asm volatile("s_waitcnt vmcnt(8)" ::: "memory");
    } else {
      asm volatile("s_waitcnt vmcnt(0)" ::: "memory");
    }
    __builtin_amdgcn_s_barrier();
    asm volatile("" ::: "memory");
    const char* As = (const char*)smd + (cur << 16);
    const char* Bs = As + 32768;
    #pragma unroll
    for (int kk = 0; kk < 64; kk += 32) {
      const int kbl = (kk + ((lane >> 4) << 3)) << 1;
      bf16x8 af[8], bfv[4];
      #pragma unroll
      for (int mi = 0; mi < 8; ++mi) {
        const int rr = wr + (mi << 4) + (lane & 15);
        af[mi] = *(const bf16x8*)(As + (rr << 7) + (kbl ^ ((rr & 7) << 4)));
      }
      #pragma unroll
      for (int ni = 0; ni < 4; ++ni) {
        const int rr = wc + (ni << 4) + (lane & 15);
        bfv[ni] = *(const bf16x8*)(Bs + (rr << 7) + (kbl ^ ((rr & 7) << 4)));
      }
      #pragma unroll
      for (int mi = 0; mi < 8; ++mi)
        #pragma unroll
        for (int ni = 0; ni < 4; ++ni)
          acc[mi][ni] = __builtin_amdgcn_mfma_f32_16x16x32_bf16(af[mi], bfv[ni], acc[mi][ni], 0, 0, 0);
    }
    asm volatile("" ::: "memory");
    __builtin_amdgcn_s_barrier();
    cur ^= 1;
  }

  if constexpr (MODE == 2) {
    // fused alpha: slice = col-quarter (wc>>6); partial over this wave's 64 cols
    const int slice = wc >> 6;
    #pragma unroll
    for (int mi = 0; mi < 8; ++mi) {
      #pragma unroll
      for (int j = 0; j < 4; ++j) {
        const long row = mTile + wr + (mi << 4) + ((lane >> 4) << 2) + j;
        const long vb = (long)batchp[row] << 8;
        float part = 0.f;
        #pragma unroll
        for (int ni = 0; ni < 4; ++ni) {
          const int col = (int)nTile + wc + (ni << 4) + (lane & 15);
          part += sigm(acc[mi][ni][j] + vw1[vb + col]) * qwf[col];
        }
        #pragma unroll
        for (int off = 1; off < 16; off <<= 1) part += __shfl_xor(part, off, 64);
        if ((lane & 15) == 0) ((float*)Cv)[(long)slice * M + row] = part;
      }
    }
  } else {
    float* C = (float*)Cv;
    #pragma unroll
    for (int ni = 0; ni < 4; ++ni) {
      const long col = nTile + wc + (ni << 4) + (lane & 15);
      if (col < N) {
        #pragma unroll
        for (int mi = 0; mi < 8; ++mi) {
          const long row = mTile + wr + (mi << 4) + ((lane >> 4) << 2);
          #pragma unroll
          for (int j = 0; j < 4; ++j)
            C[(row + j) * N + col] = acc[mi][ni][j];
        }
      }
    }
  }
}

// ---------------------------------------------------------------------------
// Fused dual-GEMM + GRUCell:  h' = GRU(aggh @ Wp^T + bih, h @ whh^T + bhh, h)
// R12-proven OCCUPANCY variant: block = 128 rows x 32 dims (8 D0-blocks),
// 8 waves (4 row-groups x 2 dim-halves), acc[2][6], ~119 VGPR under
// __launch_bounds__(512,4) -> 2 BLOCKS/CU; inter-block TLP hides drains.
// HARD RULE: no 160KB dbuf (R4/R5/R10 all +420us). LDS 56KB static.
// ---------------------------------------------------------------------------
__global__ __launch_bounds__(512, 4)
void k_ggru(const unsigned short* __restrict__ agg, const unsigned short* __restrict__ hin,
            const unsigned short* __restrict__ wpb, const unsigned short* __restrict__ whhb,
            const float* __restrict__ bih, const float* __restrict__ bhh,
            unsigned short* __restrict__ hout)
{
  __shared__ unsigned short sm[28672];          // 56 KB
  const int tid  = threadIdx.x;
  const int lane = tid & 63;
  const int wv   = tid >> 6;                    // 0..7
  const int rg   = wv >> 1;                     // row group (0..3, 32 rows each)
  const int dh   = wv & 1;                      // dim half (0/1, 16 dims)
  const int D0   = blockIdx.x << 5;             // hidden-dim base (0..224, step 32)
  const long mTile = (long)blockIdx.y << 7;

  const f32x4 z4 = {0.f, 0.f, 0.f, 0.f};
  f32x4 acc[2][6];
  #pragma unroll
  for (int i = 0; i < 2; ++i)
    #pragma unroll
    for (int g = 0; g < 6; ++g) acc[i][g] = z4;

  const int crow = lane >> 3;
  const int ckb  = (lane & 7) << 4;

  for (int k0 = 0; k0 < 256; k0 += 64) {
    // stage 56 x 1KB chunks; wave wv owns chunks wv*7 .. wv*7+6
    #pragma unroll
    for (int i = 0; i < 7; ++i) {
      const int c = wv * 7 + i;
      if (c < 32) {                             // A tiles (aggh then h), 16 chunks each
        const unsigned short* src = (c < 16) ? agg : hin;
        const int row = ((c & 15) << 3) + crow;
        const int kb  = ckb ^ ((row & 7) << 4);
        GL16(src + (mTile + row) * 256 + k0 + (kb >> 1), (char*)sm + (c << 10));
      } else {                                  // B gate chunks: 6 gates x 4 chunks
        const int g  = (c - 32) >> 2;           // 0..5
        const int lr = (((c - 32) & 3) << 3) + crow;   // 0..31
        const unsigned short* Ws = (g < 3) ? wpb : whhb;
        const long grow = (long)((g % 3) * 256 + D0 + lr);
        const int kb = ckb ^ ((lr & 7) << 4);
        GL16(Ws + grow * 256 + k0 + (kb >> 1), (char*)sm + (c << 10));
      }
    }
    __syncthreads();
    #pragma unroll
    for (int kk = 0; kk < 64; kk += 32) {
      const int kbl = (kk + ((lane >> 4) << 3)) << 1;
      bf16x8 fa[2], fh[2], fb[6];
      #pragma unroll
      for (int mi = 0; mi < 2; ++mi) {
        const int r = (rg << 5) + (mi << 4) + (lane & 15);
        const int off = (r << 7) + (kbl ^ ((r & 7) << 4));
        fa[mi] = *(const bf16x8*)((const char*)sm + off);
        fh[mi] = *(const bf16x8*)((const char*)sm + 16384 + off);
      }
      const int lr = (dh << 4) + (lane & 15);
      const int boff = (lr << 7) + (kbl ^ ((lr & 7) << 4));
      #pragma unroll
      for (int g = 0; g < 6; ++g)
        fb[g] = *(const bf16x8*)((const char*)sm + 32768 + (g << 12) + boff);
      #pragma unroll
      for (int mi = 0; mi < 2; ++mi) {
        #pragma unroll
        for (int g = 0; g < 3; ++g)
          acc[mi][g] = __builtin_amdgcn_mfma_f32_16x16x32_bf16(fa[mi], fb[g], acc[mi][g], 0, 0, 0);
        #pragma unroll
        for (int g = 3; g < 6; ++g)
          acc[mi][g] = __builtin_amdgcn_mfma_f32_16x16x32_bf16(fh[mi], fb[g], acc[mi][g], 0, 0, 0);
      }
    }
    __syncthreads();
  }

  // GRU combine (per-lane local) + write h'
  const int d = D0 + (dh << 4) + (lane & 15);
  const float bir = bih[d], biz = bih[256 + d], bin_ = bih[512 + d];
  const float bhr = bhh[d], bhz = bhh[256 + d], bhn  = bhh[512 + d];
  #pragma unroll
  for (int mi = 0; mi < 2; ++mi) {
    #pragma unroll
    for (int j = 0; j < 4; ++j) {
      const long row = mTile + (rg << 5) + (mi << 4) + ((lane >> 4) << 2) + j;
      const float hold = bf2f(hin[row * 256 + d]);
      const float r  = sigm(acc[mi][0][j] + bir + acc[mi][3][j] + bhr);
      const float z  = sigm(acc[mi][1][j] + biz + acc[mi][4][j] + bhz);
      const float n  = tanhf(acc[mi][2][j] + bin_ + r * (acc[mi][5][j] + bhn));
      hout[row * 256 + d] = f2bf((1.f - z) * n + z * hold);
    }
  }
}

// ---------------------------------------------------------------------------
// Mega-prep: one launch for emb->bf16, embedding gather, all weight cvt,
// gw straight copy, b1+b2. Block ranges:
//   [0, V8) emb cvt | [V8, V8+Nn8) gather | tail: weights/b12/gw
// ---------------------------------------------------------------------------
__global__ void k_pre(const int* __restrict__ x, const float* __restrict__ emb,
                      unsigned short* __restrict__ embb, unsigned short* __restrict__ h,
                      const float* __restrict__ wih, const float* __restrict__ whh,
                      const float* __restrict__ W1, const float* __restrict__ W2,
                      const float* __restrict__ W3, const float* __restrict__ b1,
                      const float* __restrict__ b2, const float* __restrict__ gw,
                      unsigned short* __restrict__ wihb, unsigned short* __restrict__ whhb,
                      unsigned short* __restrict__ w1b, unsigned short* __restrict__ w2b,
                      unsigned short* __restrict__ w3b, float* __restrict__ b12,
                      unsigned short* __restrict__ gwb, int V8, int Nn8)
{
  const int b = blockIdx.x, t = threadIdx.x;
  if (b < V8) {
    const long i = (long)b * 256 + t;           // one per 8 elems of emb
    const f32x4 a = *(const f32x4*)(emb + i * 8);
    const f32x4 c = *(const f32x4*)(emb + i * 8 + 4);
    *(uint4*)(embb + i * 8) = pack8(a, c);
  } else if (b < V8 + Nn8) {
    const long i = (long)(b - V8) * 256 + t;    // one per 8 dims of h
    const long node = i >> 5;
    const int  d0 = ((int)i & 31) << 3;
    const long row = (long)x[node] - 1;         // 1-based ids
    const float* p = emb + row * 256 + d0;
    const f32x4 a = *(const f32x4*)p;
    const f32x4 c = *(const f32x4*)(p + 4);
    *(uint4*)(h + node * 256 + d0) = pack8(a, c);
  } else {
    const int bw = b - V8 - Nn8;
    const float* src; unsigned short* dst; long base;
    if (bw < 96)       { src = wih; dst = wihb; base = bw; }
    else if (bw < 192) { src = whh; dst = whhb; base = bw - 96; }
    else if (bw < 224) { src = W1;  dst = w1b;  base = bw - 192; }
    else if (bw < 256) { src = W2;  dst = w2b;  base = bw - 224; }
    else if (bw < 320) { src = W3;  dst = w3b;  base = bw - 256; }
    else if (bw == 320) { b12[t] = b1[t] + b2[t]; return; }
    else               { src = gw;  dst = gwb;  base = bw - 321; }
    const long i = base * 256 + t;
    const f32x4 a = *(const f32x4*)(src + i * 8);
    const f32x4 c = *(const f32x4*)(src + i * 8 + 4);
    *(uint4*)(dst + i * 8) = pack8(a, c);
  }
}

// per-graph scatter-add: block g handles its 20 nodes / 40 edges; thread owns dim d
__global__ void k_scatter(const unsigned short* __restrict__ m, const int* __restrict__ ei,
                          unsigned short* __restrict__ agg, int E)
{
  __shared__ float aggs[20 * 256];
  __shared__ int es[40], ed[40];
  const int g = blockIdx.x;
  const int d = threadIdx.x;
  if (d < 40) es[d] = ei[g * 40 + d];
  if (d >= 128 && d < 168) ed[d - 128] = ei[E + g * 40 + (d - 128)];
  #pragma unroll
  for (int i = 0; i < 20; ++i) aggs[i * 256 + d] = 0.f;
  __syncthreads();
  for (int e = 0; e < 40; ++e) {
    const float mv = bf2f(m[(long)es[e] * 256 + d]);
    const int loc = ed[e] - g * 20;
    aggs[loc * 256 + d] += mv;     // thread-private column: no races
  }
  const long base = (long)g * (20 * 256);
  #pragma unroll
  for (int i = 0; i < 20; ++i)
    agg[base + i * 256 + d] = f2bf(aggs[i * 256 + d]);
}

// v_n gather + cat[ :256] write; last-node index via inline binsearch on batch
__global__ void k_vn(const unsigned short* __restrict__ h, const int* __restrict__ batch,
                     unsigned short* __restrict__ vn, unsigned short* __restrict__ cat, int n)
{
  const long i = (long)blockIdx.x * 256 + threadIdx.x;
  const long g = i >> 5;
  const int  d0 = ((int)i & 31) << 3;
  int lo = 0, hi = n;                     // first idx with batch[idx] > g
  while (lo < hi) { const int mid = (lo + hi) >> 1; if (batch[mid] > (int)g) hi = mid; else lo = mid + 1; }
  const uint4 v = *(const uint4*)(h + (long)(lo - 1) * 256 + d0);
  *(uint4*)(vn + g * 256 + d0) = v;
  *(uint4*)(cat + g * 512 + d0) = v;
}

__global__ void k_sg(const float* __restrict__ alph2, const float* __restrict__ qb,
                     const unsigned short* __restrict__ h, unsigned short* __restrict__ cat, int Nn)
{
  __shared__ float al[20];
  const int g = blockIdx.x, d = threadIdx.x;
  if (d < 20) {
    const int n = g * 20 + d;
    al[d] = qb[0] + alph2[n] + alph2[Nn + n] + alph2[2 * Nn + n] + alph2[3 * Nn + n];
  }
  __syncthreads();
  float s = 0.f;
  const unsigned short* hp = h + (long)g * 20 * 256 + d;
  #pragma unroll
  for (int i = 0; i < 20; ++i) s += al[i] * bf2f(hp[i * 256]);
  cat[(long)g * 512 + 256 + d] = f2bf(s);
}

// ---------------------------------------------------------------------------
extern "C" void kernel_launch(void* const* d_in, const int* in_sizes, int n_in,
                              void* d_out, int out_size, void* d_ws, size_t ws_size,
                              hipStream_t stream)
{
  const int*   x     = (const int*)  d_in[0];
  const int*   ei    = (const int*)  d_in[1];
  const int*   batch = (const int*)  d_in[2];
  const float* emb   = (const float*)d_in[3];
  const float* gw    = (const float*)d_in[4];
  const float* wih   = (const float*)d_in[5];
  const float* whh   = (const float*)d_in[6];
  const float* bih   = (const float*)d_in[7];
  const float* bhh   = (const float*)d_in[8];
  const float* W1    = (const float*)d_in[9];
  const float* b1    = (const float*)d_in[10];
  const float* W2    = (const float*)d_in[11];
  const float* b2    = (const float*)d_in[12];
  const float* qw    = (const float*)d_in[13];
  const float* qb    = (const float*)d_in[14];
  const float* W3    = (const float*)d_in[15];
  const float* b3    = (const float*)d_in[16];

  const int Nn = in_sizes[0];           // 81920 nodes
  const int E  = in_sizes[1] / 2;       // 163840 edges
  const int V  = in_sizes[3] / 256;     // 50000 vocab
  const int B  = out_size / V;          // 4096 graphs

  char* w = (char*)d_ws;
  auto take = [&](size_t bytes) { char* r = w; w += (bytes + 1023) & ~(size_t)1023; return r; };
  unsigned short* h_   = (unsigned short*)take((size_t)Nn * 256 * 2);
  unsigned short* m_   = (unsigned short*)take((size_t)Nn * 256 * 2);
  unsigned short* agg_ = (unsigned short*)take((size_t)Nn * 256 * 2);
  unsigned short* embb = (unsigned short*)take((size_t)V * 256 * 2);
  unsigned short* gwb  = (unsigned short*)take((size_t)2 * 65536 * 2);
  unsigned short* wihb = (unsigned short*)take((size_t)768 * 256 * 2);
  unsigned short* whhb = (unsigned short*)take((size_t)768 * 256 * 2);
  unsigned short* wp0  = (unsigned short*)take((size_t)768 * 256 * 2);
  unsigned short* wp1  = (unsigned short*)take((size_t)768 * 256 * 2);
  unsigned short* w1b  = (unsigned short*)take((size_t)65536 * 2);
  unsigned short* w2b  = (unsigned short*)take((size_t)65536 * 2);
  unsigned short* w3b  = (unsigned short*)take((size_t)131072 * 2);
  unsigned short* vnb  = (unsigned short*)take((size_t)B * 256 * 2);
  unsigned short* catb = (unsigned short*)take((size_t)B * 512 * 2);
  unsigned short* shb  = (unsigned short*)take((size_t)B * 256 * 2);
  float*          b12  = (float*)take(256 * 4);
  float*          alph2= (float*)take((size_t)4 * Nn * 4);
  float*          vw1  = (float*)take((size_t)B * 256 * 4);

  const int MBn = Nn / 128;             // 640
  const int MBb = B / 128;              // 32
  const int V8  = V / 8;                // 6250
  const int Nn8 = Nn / 8;               // 10240
  const int MB2 = B / 256;              // 16
  const int NB2 = (V + 255) / 256;      // 196

  // --- prep (single launch): emb cvt + gather + weight cvt ---
  k_pre<<<dim3(V8 + Nn8 + 385), 256, 0, stream>>>(x, emb, embb, h_,
      wih, whh, W1, W2, W3, b1, b2, gw, wihb, whhb, w1b, w2b, w3b, b12, gwb, V8, Nn8);

  // --- fused layer weights: Wp[i] = wih @ gw[i]^T  (768x256, tiny) ---
  gemm_bt<1, false><<<dim3(2, 6), 256, 0, stream>>>(wihb, gwb, nullptr, wp0, 768, 256, 256);
  gemm_bt<1, false><<<dim3(2, 6), 256, 0, stream>>>(wihb, gwb + 65536, nullptr, wp1, 768, 256, 256);

  // --- 2x GatedGraphConv + fused GRUCell (h ping-pongs h_ <-> m_) ---
  // m-GEMM eliminated: gi = scatter(h) @ Wp^T  (associativity of linear ops)
  unsigned short* hc = h_;
  unsigned short* mb = m_;
  for (int L = 0; L < 2; ++L) {
    k_scatter<<<dim3(B), 256, 0, stream>>>(hc, ei, agg_, E);
    k_ggru<<<dim3(8, MBn), 512, 0, stream>>>(agg_, hc, (L == 0 ? wp0 : wp1), whhb,
                                             bih, bhh, mb);
    unsigned short* t = hc; hc = mb; mb = t;    // h' now lives in old m buffer
  }
  // after 2 swaps hc == h_ again

  // --- attention readout ---
  k_vn<<<dim3(B * 32 / 256), 256, 0, stream>>>(hc, batch, vnb, catb, Nn);
  gemm_bt<0, true><<<dim3(2, MBb), 256, 0, stream>>>(vnb, w1b, b12, vw1, B, 256, 256);
  // fused alpha on the 256^2 schedule: grid (1, Nn/256)
  gemm256<2><<<dim3(1, Nn / 256), 512, 131072, stream>>>(hc, w2b, alph2,
                                                         vw1, qw, batch, Nn, 256, 256);
  k_sg<<<dim3(B), 256, 0, stream>>>(alph2, qb, hc, catb, Nn);
  gemm_bt<1, true><<<dim3(2, MBb), 256, 0, stream>>>(catb, w3b, b3, shb, B, 256, 512);

  // --- scores = s_h @ emb^T -> d_out (f32); 256^2-tile, 2-D grid, plain
  // stores (R12-proven; R13's NT+XCD variant reverted) ---
  gemm256<0><<<dim3(NB2, MB2), 512, 131072, stream>>>(shb, embb, (float*)d_out,
                                                      nullptr, nullptr, nullptr, B, V, 256);

  (void)n_in; (void)ws_size;
}

// Round 15
// 666.376 us; speedup vs baseline: 1.0530x; 1.0273x over previous
//
#include <hip/hip_runtime.h>

typedef __attribute__((ext_vector_type(8))) __bf16 bf16x8;
typedef __attribute__((ext_vector_type(4))) float f32x4;

#define DEV __device__ __forceinline__

DEV unsigned short f2bf(float f) {
  unsigned u = __float_as_uint(f);
  u = (u + 0x7fffu + ((u >> 16) & 1u)) >> 16;   // round-to-nearest-even
  return (unsigned short)u;
}
DEV float bf2f(unsigned short s) { return __uint_as_float(((unsigned)s) << 16); }
DEV float sigm(float x) { return 1.f / (1.f + expf(-x)); }

DEV uint4 pack8(f32x4 a, f32x4 b) {
  uint4 o;
  o.x = (unsigned)f2bf(a[0]) | ((unsigned)f2bf(a[1]) << 16);
  o.y = (unsigned)f2bf(a[2]) | ((unsigned)f2bf(a[3]) << 16);
  o.z = (unsigned)f2bf(b[0]) | ((unsigned)f2bf(b[1]) << 16);
  o.w = (unsigned)f2bf(b[2]) | ((unsigned)f2bf(b[3]) << 16);
  return o;
}

#define GL16(SRC, LDSB)                                                                    \
  __builtin_amdgcn_global_load_lds(                                                       \
      (const __attribute__((address_space(1))) unsigned int*)(SRC),                       \
      (__attribute__((address_space(3))) unsigned int*)(LDSB), 16, 0, 0)

// ---------------------------------------------------------------------------
// GEMM: C[M x N] = A[M x K] * B^T  (B stored [N x K] row-major bf16)
// R8-proven: 128x128 tile, BK=64, 4 waves, dbuf 64KB LDS, counted vmcnt(8)
// + raw s_barrier. XOR swizzle involution (rule #21).
// Grid: x = N tiles, y = M tiles.
// MODE: 0 f32 out, 1 bf16 out, 2 fused-alpha partials (R15: alpha back here —
// gemm256<2>'s 320x1-block/CU launch had a 2-round tail on 256 CUs, ~+18us;
// 1280 small blocks load-balance cleanly).
// ---------------------------------------------------------------------------
template<int MODE, bool BIAS>
__global__ __launch_bounds__(256)
void gemm_bt(const unsigned short* __restrict__ A, const unsigned short* __restrict__ Bm,
             const float* __restrict__ bias, void* __restrict__ Cv,
             const float* __restrict__ vw1, const float* __restrict__ qwf,
             const int* __restrict__ batchp, int M, int N, int K)
{
  __shared__ unsigned short sm[32768];          // 64 KB: 2 x {As[128][64], Bs[128][64]}

  const int tid  = threadIdx.x;
  const int lane = tid & 63;
  const int wv   = tid >> 6;
  const int wr   = (wv >> 1) << 6;              // wave row offset (0/64)
  const int wc   = (wv & 1) << 6;               // wave col offset (0/64)
  const long mTile = (long)blockIdx.y << 7;
  const long nTile = (long)blockIdx.x << 7;

  const f32x4 z4 = {0.f, 0.f, 0.f, 0.f};
  f32x4 acc[4][4];
  #pragma unroll
  for (int i = 0; i < 4; ++i)
    #pragma unroll
    for (int j = 0; j < 4; ++j) acc[i][j] = z4;

  const int crow = lane >> 3;                   // row within 8-row chunk
  const int ckb  = (lane & 7) << 4;             // linear kbyte of this lane's 16B

  auto stage = [&](int buf, int k0) {           // exactly 8 gload_lds per thread
    char* base = (char*)sm + (buf << 15);
    #pragma unroll
    for (int i = 0; i < 4; ++i) {
      const int c   = (wv << 2) + i;            // chunk 0..15
      const int row = (c << 3) + crow;          // tile row 0..127
      const int kb  = ckb ^ ((row & 7) << 4);   // pre-swizzled source kbyte
      const unsigned short* sA = A + (mTile + row) * K + k0 + (kb >> 1);
      GL16(sA, base + (c << 10));
      int bn = (int)nTile + row; bn = bn < N ? bn : (N - 1);   // clamp OOB cols
      const unsigned short* sB = Bm + (long)bn * K + k0 + (kb >> 1);
      GL16(sB, base + 16384 + (c << 10));
    }
  };

  const int nt = K >> 6;
  stage(0, 0);
  int cur = 0;
  for (int t = 0; t < nt; ++t) {
    if (t + 1 < nt) {
      stage(cur ^ 1, (t + 1) << 6);             // prefetch: stays in flight
      asm volatile("s_waitcnt vmcnt(8)" ::: "memory");   // tile t landed
    } else {
      asm volatile("s_waitcnt vmcnt(0)" ::: "memory");
    }
    __builtin_amdgcn_s_barrier();               // raw: does NOT drain vmcnt
    asm volatile("" ::: "memory");
    const char* As = (const char*)sm + (cur << 15);
    const char* Bs = As + 16384;
    #pragma unroll
    for (int kk = 0; kk < 64; kk += 32) {
      const int kbl = (kk + ((lane >> 4) << 3)) << 1;   // logical kbyte of fragment
      bf16x8 af[4], bfv[4];
      #pragma unroll
      for (int mi = 0; mi < 4; ++mi) {
        const int rr = wr + (mi << 4) + (lane & 15);
        af[mi] = *(const bf16x8*)(As + (rr << 7) + (kbl ^ ((rr & 7) << 4)));
      }
      #pragma unroll
      for (int ni = 0; ni < 4; ++ni) {
        const int rr = wc + (ni << 4) + (lane & 15);
        bfv[ni] = *(const bf16x8*)(Bs + (rr << 7) + (kbl ^ ((rr & 7) << 4)));
      }
      #pragma unroll
      for (int mi = 0; mi < 4; ++mi)
        #pragma unroll
        for (int ni = 0; ni < 4; ++ni)
          acc[mi][ni] = __builtin_amdgcn_mfma_f32_16x16x32_bf16(af[mi], bfv[ni], acc[mi][ni], 0, 0, 0);
    }
    asm volatile("" ::: "memory");              // pin ds_reads above barrier
    __builtin_amdgcn_s_barrier();               // buf free for stage(t+2)
    cur ^= 1;
  }

  if constexpr (MODE == 2) {
    // fused alpha: partial = sum_col sigm(vw1[batch[row]][col]+gemm) * qw[col]
    // one slice per (nBlk, wave-col-half); k_sg sums 4 slices + qb.
    const int slice = (int)blockIdx.x * 2 + (wc >> 6);
    #pragma unroll
    for (int mi = 0; mi < 4; ++mi) {
      #pragma unroll
      for (int j = 0; j < 4; ++j) {
        const long row = mTile + wr + (mi << 4) + ((lane >> 4) << 2) + j;
        const long vb = (long)batchp[row] << 8;
        float part = 0.f;
        #pragma unroll
        for (int ni = 0; ni < 4; ++ni) {
          const int col = (int)nTile + wc + (ni << 4) + (lane & 15);
          part += sigm(acc[mi][ni][j] + vw1[vb + col]) * qwf[col];
        }
        #pragma unroll
        for (int off = 1; off < 16; off <<= 1) part += __shfl_xor(part, off, 64);
        if ((lane & 15) == 0) ((float*)Cv)[(long)slice * M + row] = part;
      }
    }
  } else {
    // C/D layout col=lane&15, row=(lane>>4)*4+j (m89-verified)
    #pragma unroll
    for (int ni = 0; ni < 4; ++ni) {
      const long col = nTile + wc + (ni << 4) + (lane & 15);
      if (col < N) {
        float bv = 0.f;
        if constexpr (BIAS) bv = bias[col];
        #pragma unroll
        for (int mi = 0; mi < 4; ++mi) {
          const long row = mTile + wr + (mi << 4) + ((lane >> 4) << 2);
          #pragma unroll
          for (int j = 0; j < 4; ++j) {
            const float v = acc[mi][ni][j] + bv;
            if constexpr (MODE == 1) ((unsigned short*)Cv)[(row + j) * N + col] = f2bf(v);
            else                     ((float*)Cv)[(row + j) * N + col] = v;
          }
        }
      }
    }
  }
}

// ---------------------------------------------------------------------------
// 256x256-tile GEMM for the scores matmul (R9-proven counted-vmcnt schedule):
// 8 waves (2x4), per-wave 128x64 output, acc[8][4], 128KB dynamic LDS dbuf
// (128KB fast; 160KB is a cliff — R4/R5/R10). 2-D grid, plain stores
// (R13's NT+XCD variant regressed; reverted). f32 out, no bias, col-guarded.
// ---------------------------------------------------------------------------
__global__ __launch_bounds__(512, 2)
void gemm256(const unsigned short* __restrict__ A, const unsigned short* __restrict__ Bm,
             float* __restrict__ C, int M, int N, int K)
{
  extern __shared__ unsigned short smd[];       // 128 KB: 2 x {As[256][64], Bs[256][64]}
  const int tid  = threadIdx.x;
  const int lane = tid & 63;
  const int wv   = tid >> 6;                    // 0..7
  const int wr   = (wv >> 2) << 7;              // wave row offset (0/128)
  const int wc   = (wv & 3) << 6;               // wave col offset (0/64/128/192)
  const long mTile = (long)blockIdx.y << 8;
  const long nTile = (long)blockIdx.x << 8;

  const f32x4 z4 = {0.f, 0.f, 0.f, 0.f};
  f32x4 acc[8][4];
  #pragma unroll
  for (int i = 0; i < 8; ++i)
    #pragma unroll
    for (int j = 0; j < 4; ++j) acc[i][j] = z4;

  const int crow = lane >> 3;                   // row within 8-row chunk
  const int ckb  = (lane & 7) << 4;

  auto stage = [&](int buf, int k0) {           // exactly 8 gload_lds per thread
    char* base = (char*)smd + (buf << 16);
    #pragma unroll
    for (int i = 0; i < 4; ++i) {
      const int c   = (wv << 2) + i;            // chunk 0..31
      const int row = (c << 3) + crow;          // tile row 0..255
      const int kb  = ckb ^ ((row & 7) << 4);
      const unsigned short* sA = A + (mTile + row) * K + k0 + (kb >> 1);
      GL16(sA, base + (c << 10));
      int bn = (int)nTile + row; bn = bn < N ? bn : (N - 1);
      const unsigned short* sB = Bm + (long)bn * K + k0 + (kb >> 1);
      GL16(sB, base + 32768 + (c << 10));
    }
  };

  const int nt = K >> 6;
  stage(0, 0);
  int cur = 0;
  for (int t = 0; t < nt; ++t) {
    if (t + 1 < nt) {
      stage(cur ^ 1, (t + 1) << 6);
      asm volatile("s_waitcnt vmcnt(8)" ::: "memory");
    } else {
      asm volatile("s_waitcnt vmcnt(0)" ::: "memory");
    }
    __builtin_amdgcn_s_barrier();
    asm volatile("" ::: "memory");
    const char* As = (const char*)smd + (cur << 16);
    const char* Bs = As + 32768;
    #pragma unroll
    for (int kk = 0; kk < 64; kk += 32) {
      const int kbl = (kk + ((lane >> 4) << 3)) << 1;
      bf16x8 af[8], bfv[4];
      #pragma unroll
      for (int mi = 0; mi < 8; ++mi) {
        const int rr = wr + (mi << 4) + (lane & 15);
        af[mi] = *(const bf16x8*)(As + (rr << 7) + (kbl ^ ((rr & 7) << 4)));
      }
      #pragma unroll
      for (int ni = 0; ni < 4; ++ni) {
        const int rr = wc + (ni << 4) + (lane & 15);
        bfv[ni] = *(const bf16x8*)(Bs + (rr << 7) + (kbl ^ ((rr & 7) << 4)));
      }
      #pragma unroll
      for (int mi = 0; mi < 8; ++mi)
        #pragma unroll
        for (int ni = 0; ni < 4; ++ni)
          acc[mi][ni] = __builtin_amdgcn_mfma_f32_16x16x32_bf16(af[mi], bfv[ni], acc[mi][ni], 0, 0, 0);
    }
    asm volatile("" ::: "memory");
    __builtin_amdgcn_s_barrier();
    cur ^= 1;
  }

  #pragma unroll
  for (int ni = 0; ni < 4; ++ni) {
    const long col = nTile + wc + (ni << 4) + (lane & 15);
    if (col < N) {
      #pragma unroll
      for (int mi = 0; mi < 8; ++mi) {
        const long row = mTile + wr + (mi << 4) + ((lane >> 4) << 2);
        #pragma unroll
        for (int j = 0; j < 4; ++j)
          C[(row + j) * N + col] = acc[mi][ni][j];
      }
    }
  }
}

// ---------------------------------------------------------------------------
// Fused dual-GEMM + GRUCell:  h' = GRU(aggh @ Wp^T + bih, h @ whh^T + bhh, h)
// R12-proven OCCUPANCY variant: block = 128 rows x 32 dims (8 D0-blocks),
// 8 waves (4 row-groups x 2 dim-halves), acc[2][6], ~119 VGPR under
// __launch_bounds__(512,4) -> 2 BLOCKS/CU; inter-block TLP hides drains.
// HARD RULE: no 160KB dbuf (R4/R5/R10 all +420us). LDS 56KB static.
// ---------------------------------------------------------------------------
__global__ __launch_bounds__(512, 4)
void k_ggru(const unsigned short* __restrict__ agg, const unsigned short* __restrict__ hin,
            const unsigned short* __restrict__ wpb, const unsigned short* __restrict__ whhb,
            const float* __restrict__ bih, const float* __restrict__ bhh,
            unsigned short* __restrict__ hout)
{
  __shared__ unsigned short sm[28672];          // 56 KB
  const int tid  = threadIdx.x;
  const int lane = tid & 63;
  const int wv   = tid >> 6;                    // 0..7
  const int rg   = wv >> 1;                     // row group (0..3, 32 rows each)
  const int dh   = wv & 1;                      // dim half (0/1, 16 dims)
  const int D0   = blockIdx.x << 5;             // hidden-dim base (0..224, step 32)
  const long mTile = (long)blockIdx.y << 7;

  const f32x4 z4 = {0.f, 0.f, 0.f, 0.f};
  f32x4 acc[2][6];
  #pragma unroll
  for (int i = 0; i < 2; ++i)
    #pragma unroll
    for (int g = 0; g < 6; ++g) acc[i][g] = z4;

  const int crow = lane >> 3;
  const int ckb  = (lane & 7) << 4;

  for (int k0 = 0; k0 < 256; k0 += 64) {
    // stage 56 x 1KB chunks; wave wv owns chunks wv*7 .. wv*7+6
    #pragma unroll
    for (int i = 0; i < 7; ++i) {
      const int c = wv * 7 + i;
      if (c < 32) {                             // A tiles (aggh then h), 16 chunks each
        const unsigned short* src = (c < 16) ? agg : hin;
        const int row = ((c & 15) << 3) + crow;
        const int kb  = ckb ^ ((row & 7) << 4);
        GL16(src + (mTile + row) * 256 + k0 + (kb >> 1), (char*)sm + (c << 10));
      } else {                                  // B gate chunks: 6 gates x 4 chunks
        const int g  = (c - 32) >> 2;           // 0..5
        const int lr = (((c - 32) & 3) << 3) + crow;   // 0..31
        const unsigned short* Ws = (g < 3) ? wpb : whhb;
        const long grow = (long)((g % 3) * 256 + D0 + lr);
        const int kb = ckb ^ ((lr & 7) << 4);
        GL16(Ws + grow * 256 + k0 + (kb >> 1), (char*)sm + (c << 10));
      }
    }
    __syncthreads();
    #pragma unroll
    for (int kk = 0; kk < 64; kk += 32) {
      const int kbl = (kk + ((lane >> 4) << 3)) << 1;
      bf16x8 fa[2], fh[2], fb[6];
      #pragma unroll
      for (int mi = 0; mi < 2; ++mi) {
        const int r = (rg << 5) + (mi << 4) + (lane & 15);
        const int off = (r << 7) + (kbl ^ ((r & 7) << 4));
        fa[mi] = *(const bf16x8*)((const char*)sm + off);
        fh[mi] = *(const bf16x8*)((const char*)sm + 16384 + off);
      }
      const int lr = (dh << 4) + (lane & 15);
      const int boff = (lr << 7) + (kbl ^ ((lr & 7) << 4));
      #pragma unroll
      for (int g = 0; g < 6; ++g)
        fb[g] = *(const bf16x8*)((const char*)sm + 32768 + (g << 12) + boff);
      #pragma unroll
      for (int mi = 0; mi < 2; ++mi) {
        #pragma unroll
        for (int g = 0; g < 3; ++g)
          acc[mi][g] = __builtin_amdgcn_mfma_f32_16x16x32_bf16(fa[mi], fb[g], acc[mi][g], 0, 0, 0);
        #pragma unroll
        for (int g = 3; g < 6; ++g)
          acc[mi][g] = __builtin_amdgcn_mfma_f32_16x16x32_bf16(fh[mi], fb[g], acc[mi][g], 0, 0, 0);
      }
    }
    __syncthreads();
  }

  // GRU combine (per-lane local) + write h'
  const int d = D0 + (dh << 4) + (lane & 15);
  const float bir = bih[d], biz = bih[256 + d], bin_ = bih[512 + d];
  const float bhr = bhh[d], bhz = bhh[256 + d], bhn  = bhh[512 + d];
  #pragma unroll
  for (int mi = 0; mi < 2; ++mi) {
    #pragma unroll
    for (int j = 0; j < 4; ++j) {
      const long row = mTile + (rg << 5) + (mi << 4) + ((lane >> 4) << 2) + j;
      const float hold = bf2f(hin[row * 256 + d]);
      const float r  = sigm(acc[mi][0][j] + bir + acc[mi][3][j] + bhr);
      const float z  = sigm(acc[mi][1][j] + biz + acc[mi][4][j] + bhz);
      const float n  = tanhf(acc[mi][2][j] + bin_ + r * (acc[mi][5][j] + bhn));
      hout[row * 256 + d] = f2bf((1.f - z) * n + z * hold);
    }
  }
}

// ---------------------------------------------------------------------------
// Mega-prep: one launch for emb->bf16, embedding gather, all weight cvt,
// gw straight copy, b1+b2. Block ranges:
//   [0, V8) emb cvt | [V8, V8+Nn8) gather | tail: weights/b12/gw
// ---------------------------------------------------------------------------
__global__ void k_pre(const int* __restrict__ x, const float* __restrict__ emb,
                      unsigned short* __restrict__ embb, unsigned short* __restrict__ h,
                      const float* __restrict__ wih, const float* __restrict__ whh,
                      const float* __restrict__ W1, const float* __restrict__ W2,
                      const float* __restrict__ W3, const float* __restrict__ b1,
                      const float* __restrict__ b2, const float* __restrict__ gw,
                      unsigned short* __restrict__ wihb, unsigned short* __restrict__ whhb,
                      unsigned short* __restrict__ w1b, unsigned short* __restrict__ w2b,
                      unsigned short* __restrict__ w3b, float* __restrict__ b12,
                      unsigned short* __restrict__ gwb, int V8, int Nn8)
{
  const int b = blockIdx.x, t = threadIdx.x;
  if (b < V8) {
    const long i = (long)b * 256 + t;           // one per 8 elems of emb
    const f32x4 a = *(const f32x4*)(emb + i * 8);
    const f32x4 c = *(const f32x4*)(emb + i * 8 + 4);
    *(uint4*)(embb + i * 8) = pack8(a, c);
  } else if (b < V8 + Nn8) {
    const long i = (long)(b - V8) * 256 + t;    // one per 8 dims of h
    const long node = i >> 5;
    const int  d0 = ((int)i & 31) << 3;
    const long row = (long)x[node] - 1;         // 1-based ids
    const float* p = emb + row * 256 + d0;
    const f32x4 a = *(const f32x4*)p;
    const f32x4 c = *(const f32x4*)(p + 4);
    *(uint4*)(h + node * 256 + d0) = pack8(a, c);
  } else {
    const int bw = b - V8 - Nn8;
    const float* src; unsigned short* dst; long base;
    if (bw < 96)       { src = wih; dst = wihb; base = bw; }
    else if (bw < 192) { src = whh; dst = whhb; base = bw - 96; }
    else if (bw < 224) { src = W1;  dst = w1b;  base = bw - 192; }
    else if (bw < 256) { src = W2;  dst = w2b;  base = bw - 224; }
    else if (bw < 320) { src = W3;  dst = w3b;  base = bw - 256; }
    else if (bw == 320) { b12[t] = b1[t] + b2[t]; return; }
    else               { src = gw;  dst = gwb;  base = bw - 321; }
    const long i = base * 256 + t;
    const f32x4 a = *(const f32x4*)(src + i * 8);
    const f32x4 c = *(const f32x4*)(src + i * 8 + 4);
    *(uint4*)(dst + i * 8) = pack8(a, c);
  }
}

// per-graph scatter-add: block g handles its 20 nodes / 40 edges; thread owns dim d
__global__ void k_scatter(const unsigned short* __restrict__ m, const int* __restrict__ ei,
                          unsigned short* __restrict__ agg, int E)
{
  __shared__ float aggs[20 * 256];
  __shared__ int es[40], ed[40];
  const int g = blockIdx.x;
  const int d = threadIdx.x;
  if (d < 40) es[d] = ei[g * 40 + d];
  if (d >= 128 && d < 168) ed[d - 128] = ei[E + g * 40 + (d - 128)];
  #pragma unroll
  for (int i = 0; i < 20; ++i) aggs[i * 256 + d] = 0.f;
  __syncthreads();
  for (int e = 0; e < 40; ++e) {
    const float mv = bf2f(m[(long)es[e] * 256 + d]);
    const int loc = ed[e] - g * 20;
    aggs[loc * 256 + d] += mv;     // thread-private column: no races
  }
  const long base = (long)g * (20 * 256);
  #pragma unroll
  for (int i = 0; i < 20; ++i)
    agg[base + i * 256 + d] = f2bf(aggs[i * 256 + d]);
}

// v_n gather + cat[ :256] write; last-node index via inline binsearch on batch
__global__ void k_vn(const unsigned short* __restrict__ h, const int* __restrict__ batch,
                     unsigned short* __restrict__ vn, unsigned short* __restrict__ cat, int n)
{
  const long i = (long)blockIdx.x * 256 + threadIdx.x;
  const long g = i >> 5;
  const int  d0 = ((int)i & 31) << 3;
  int lo = 0, hi = n;                     // first idx with batch[idx] > g
  while (lo < hi) { const int mid = (lo + hi) >> 1; if (batch[mid] > (int)g) hi = mid; else lo = mid + 1; }
  const uint4 v = *(const uint4*)(h + (long)(lo - 1) * 256 + d0);
  *(uint4*)(vn + g * 256 + d0) = v;
  *(uint4*)(cat + g * 512 + d0) = v;
}

__global__ void k_sg(const float* __restrict__ alph2, const float* __restrict__ qb,
                     const unsigned short* __restrict__ h, unsigned short* __restrict__ cat, int Nn)
{
  __shared__ float al[20];
  const int g = blockIdx.x, d = threadIdx.x;
  if (d < 20) {
    const int n = g * 20 + d;
    al[d] = qb[0] + alph2[n] + alph2[Nn + n] + alph2[2 * Nn + n] + alph2[3 * Nn + n];
  }
  __syncthreads();
  float s = 0.f;
  const unsigned short* hp = h + (long)g * 20 * 256 + d;
  #pragma unroll
  for (int i = 0; i < 20; ++i) s += al[i] * bf2f(hp[i * 256]);
  cat[(long)g * 512 + 256 + d] = f2bf(s);
}

// ---------------------------------------------------------------------------
extern "C" void kernel_launch(void* const* d_in, const int* in_sizes, int n_in,
                              void* d_out, int out_size, void* d_ws, size_t ws_size,
                              hipStream_t stream)
{
  const int*   x     = (const int*)  d_in[0];
  const int*   ei    = (const int*)  d_in[1];
  const int*   batch = (const int*)  d_in[2];
  const float* emb   = (const float*)d_in[3];
  const float* gw    = (const float*)d_in[4];
  const float* wih   = (const float*)d_in[5];
  const float* whh   = (const float*)d_in[6];
  const float* bih   = (const float*)d_in[7];
  const float* bhh   = (const float*)d_in[8];
  const float* W1    = (const float*)d_in[9];
  const float* b1    = (const float*)d_in[10];
  const float* W2    = (const float*)d_in[11];
  const float* b2    = (const float*)d_in[12];
  const float* qw    = (const float*)d_in[13];
  const float* qb    = (const float*)d_in[14];
  const float* W3    = (const float*)d_in[15];
  const float* b3    = (const float*)d_in[16];

  const int Nn = in_sizes[0];           // 81920 nodes
  const int E  = in_sizes[1] / 2;       // 163840 edges
  const int V  = in_sizes[3] / 256;     // 50000 vocab
  const int B  = out_size / V;          // 4096 graphs

  char* w = (char*)d_ws;
  auto take = [&](size_t bytes) { char* r = w; w += (bytes + 1023) & ~(size_t)1023; return r; };
  unsigned short* h_   = (unsigned short*)take((size_t)Nn * 256 * 2);
  unsigned short* m_   = (unsigned short*)take((size_t)Nn * 256 * 2);
  unsigned short* agg_ = (unsigned short*)take((size_t)Nn * 256 * 2);
  unsigned short* embb = (unsigned short*)take((size_t)V * 256 * 2);
  unsigned short* gwb  = (unsigned short*)take((size_t)2 * 65536 * 2);
  unsigned short* wihb = (unsigned short*)take((size_t)768 * 256 * 2);
  unsigned short* whhb = (unsigned short*)take((size_t)768 * 256 * 2);
  unsigned short* wp0  = (unsigned short*)take((size_t)768 * 256 * 2);
  unsigned short* wp1  = (unsigned short*)take((size_t)768 * 256 * 2);
  unsigned short* w1b  = (unsigned short*)take((size_t)65536 * 2);
  unsigned short* w2b  = (unsigned short*)take((size_t)65536 * 2);
  unsigned short* w3b  = (unsigned short*)take((size_t)131072 * 2);
  unsigned short* vnb  = (unsigned short*)take((size_t)B * 256 * 2);
  unsigned short* catb = (unsigned short*)take((size_t)B * 512 * 2);
  unsigned short* shb  = (unsigned short*)take((size_t)B * 256 * 2);
  float*          b12  = (float*)take(256 * 4);
  float*          alph2= (float*)take((size_t)4 * Nn * 4);
  float*          vw1  = (float*)take((size_t)B * 256 * 4);

  const int MBn = Nn / 128;             // 640
  const int MBb = B / 128;              // 32
  const int V8  = V / 8;                // 6250
  const int Nn8 = Nn / 8;               // 10240
  const int MB2 = B / 256;              // 16
  const int NB2 = (V + 255) / 256;      // 196

  // --- prep (single launch): emb cvt + gather + weight cvt ---
  k_pre<<<dim3(V8 + Nn8 + 385), 256, 0, stream>>>(x, emb, embb, h_,
      wih, whh, W1, W2, W3, b1, b2, gw, wihb, whhb, w1b, w2b, w3b, b12, gwb, V8, Nn8);

  // --- fused layer weights: Wp[i] = wih @ gw[i]^T  (768x256, tiny) ---
  gemm_bt<1, false><<<dim3(2, 6), 256, 0, stream>>>(wihb, gwb, nullptr, wp0,
                                                    nullptr, nullptr, nullptr, 768, 256, 256);
  gemm_bt<1, false><<<dim3(2, 6), 256, 0, stream>>>(wihb, gwb + 65536, nullptr, wp1,
                                                    nullptr, nullptr, nullptr, 768, 256, 256);

  // --- 2x GatedGraphConv + fused GRUCell (h ping-pongs h_ <-> m_) ---
  // m-GEMM eliminated: gi = scatter(h) @ Wp^T  (associativity of linear ops)
  unsigned short* hc = h_;
  unsigned short* mb = m_;
  for (int L = 0; L < 2; ++L) {
    k_scatter<<<dim3(B), 256, 0, stream>>>(hc, ei, agg_, E);
    k_ggru<<<dim3(8, MBn), 512, 0, stream>>>(agg_, hc, (L == 0 ? wp0 : wp1), whhb,
                                             bih, bhh, mb);
    unsigned short* t = hc; hc = mb; mb = t;    // h' now lives in old m buffer
  }
  // after 2 swaps hc == h_ again

  // --- attention readout ---
  k_vn<<<dim3(B * 32 / 256), 256, 0, stream>>>(hc, batch, vnb, catb, Nn);
  gemm_bt<0, true><<<dim3(2, MBb), 256, 0, stream>>>(vnb, w1b, b12, vw1,
                                                     nullptr, nullptr, nullptr, B, 256, 256);
  // fused alpha on gemm_bt (R15: 1280 small blocks load-balance; gemm256's
  // 320x1-block/CU launch had a 2-round tail ~+18us)
  gemm_bt<2, false><<<dim3(2, MBn), 256, 0, stream>>>(hc, w2b, nullptr, alph2,
                                                      vw1, qw, batch, Nn, 256, 256);
  k_sg<<<dim3(B), 256, 0, stream>>>(alph2, qb, hc, catb, Nn);
  gemm_bt<1, true><<<dim3(2, MBb), 256, 0, stream>>>(catb, w3b, b3, shb,
                                                     nullptr, nullptr, nullptr, B, 256, 512);

  // --- scores = s_h @ emb^T -> d_out (f32); 256^2-tile, 2-D grid, plain stores ---
  gemm256<<<dim3(NB2, MB2), 512, 131072, stream>>>(shb, embb, (float*)d_out, B, V, 256);

  (void)n_in; (void)ws_size;
}